// Round 16
// baseline (103.025 us; speedup 1.0000x reference)
//
#include <hip/hip_runtime.h>
#include <hip/hip_bf16.h>
#include <math.h>

// CoSent clustering loss on MI355X — round 16 (MEASUREMENT PROBE).
// Identical to r15 except cosent_main is launched 3x (bit-identical output,
// deterministic). main_us = (dur_r16 - dur_r15) / 2. This resolves the
// main-vs-overhead split that has been invisible since r9 (fillBuffer owns
// all rocprof top-5 slots at ~40us).

typedef __attribute__((ext_vector_type(2))) long l2;     // two fp8 frags
typedef __attribute__((ext_vector_type(4))) float f32x4;

#define N_EMB 8192
#define D_EMB 256
#define NUM_LABELS 128
#define PAN 128
#define NPAN (N_EMB / PAN)           // 64
#define NTRI (NPAN * (NPAN + 1) / 2) // 2080 = 8 * 260

// ---- DPP 16-lane reduction helpers ----
template <int CTRL>
__device__ __forceinline__ float dpp_add(float x) {
    int y = __builtin_amdgcn_update_dpp(0, __builtin_bit_cast(int, x),
                                        CTRL, 0xF, 0xF, false);
    return x + __builtin_bit_cast(float, y);
}
__device__ __forceinline__ float red16(float x) {
    x = dpp_add<0xB1>(x);    // quad_perm xor1
    x = dpp_add<0x4E>(x);    // quad_perm xor2
    x = dpp_add<0x124>(x);   // row_ror:4
    x = dpp_add<0x128>(x);   // row_ror:8
    return x;
}

__device__ __forceinline__ float exp2hw(float x) {
    float r;
    asm("v_exp_f32 %0, %1" : "=v"(r) : "v"(x));
    return r;
}

__device__ __forceinline__ unsigned packbf(float a, float b) {
    unsigned ua = __builtin_bit_cast(unsigned, a);
    unsigned ub = __builtin_bit_cast(unsigned, b);
    ua += 0x7FFFu + ((ua >> 16) & 1u);   // RTNE to bf16
    ub += 0x7FFFu + ((ub >> 16) & 1u);
    return (ua >> 16) | (ub & 0xFFFF0000u);
}

// ---------------------------------------------------------------- normalize
__global__ __launch_bounds__(256) void normalize_kernel(const float* __restrict__ emb,
                                                        const float* __restrict__ scale,
                                                        char* __restrict__ e8) {
    const int wid = threadIdx.x >> 6, lane = threadIdx.x & 63;
    const int row = blockIdx.x * 4 + wid;
    const f32x4 x = *(const f32x4*)(emb + (size_t)row * D_EMB + lane * 4);
    float ss = x[0]*x[0] + x[1]*x[1] + x[2]*x[2] + x[3]*x[3];
    #pragma unroll
    for (int off = 32; off >= 1; off >>= 1) ss += __shfl_xor(ss, off);
    const float r = 1.0f / fmaxf(sqrtf(ss), 1e-12f);
    const float ps = sqrtf(scale[0] * 1.44269504088896f) * r;
    int v = __builtin_amdgcn_cvt_pk_fp8_f32(x[0] * ps, x[1] * ps, 0, false);
    v = __builtin_amdgcn_cvt_pk_fp8_f32(x[2] * ps, x[3] * ps, v, true);
    const int u    = lane >> 4;
    const int half = (lane >> 3) & 1;
    const int lp   = ((lane >> 1) & 3) * 16 + (row & 15);
    const int j0   = (lane & 1) * 4;
    char* dst = e8 + ((size_t)(row >> 4) * 4 + u) * 1024 + lp * 16 + half * 8 + j0;
    *(unsigned*)dst = (unsigned)v;
}

// ---- pinned coalesced superfrag load: SGPR base + VGPR offset + literal ----
#define LOADF(dst, voff, sb, OFFSTR) \
    asm volatile("global_load_dwordx4 %0, %1, %2 offset:" OFFSTR \
                 : "=v"(dst) : "v"(voff), "s"(sb))

#define ISSUE(PA_, PB_, OFFSTR) \
    LOADF(PA_[0], voA[0], sbA, OFFSTR); LOADF(PA_[1], voA[1], sbA, OFFSTR); \
    LOADF(PA_[2], voA[2], sbA, OFFSTR); LOADF(PA_[3], voA[3], sbA, OFFSTR); \
    LOADF(PB_[0], voB[0], sbB, OFFSTR); LOADF(PB_[1], voB[1], sbB, OFFSTR); \
    LOADF(PB_[2], voB[2], sbB, OFFSTR); LOADF(PB_[3], voB[3], sbB, OFFSTR)

#define WAITV(NSTR) \
    asm volatile("s_waitcnt vmcnt(" NSTR ")" ::: "memory"); \
    __builtin_amdgcn_sched_barrier(0)

#define MF8(a, b, c) __builtin_amdgcn_mfma_f32_16x16x32_fp8_fp8(a, b, c, 0, 0, 0)

#define MROW(PA_, PB_, mi, H) \
    acc[mi][0] = MF8(PA_[mi][H], PB_[0][H], acc[mi][0]); \
    acc[mi][1] = MF8(PA_[mi][H], PB_[1][H], acc[mi][1]); \
    acc[mi][2] = MF8(PA_[mi][H], PB_[2][H], acc[mi][2]); \
    acc[mi][3] = MF8(PA_[mi][H], PB_[3][H], acc[mi][3]);

#define MFMA32(PA_, PB_) \
    __builtin_amdgcn_s_setprio(1); \
    MROW(PA_, PB_, 0, 0) MROW(PA_, PB_, 1, 0) MROW(PA_, PB_, 2, 0) MROW(PA_, PB_, 3, 0) \
    MROW(PA_, PB_, 0, 1) MROW(PA_, PB_, 1, 1) MROW(PA_, PB_, 2, 1) MROW(PA_, PB_, 3, 1) \
    __builtin_amdgcn_s_setprio(0)

// ----------------------------------------------------------------- main GEMM
__global__ __launch_bounds__(256, 3) void cosent_main(const char* __restrict__ e8,
                                                      const int* __restrict__ labels,
                                                      unsigned* __restrict__ wsAB) {
    __shared__ float rowsc[2][PAN][2];
    __shared__ float colsc[2][PAN][2];
    __shared__ int labR[PAN], labC[PAN];

    const int bid = blockIdx.x;
    const int swz = (bid & 7) * 260 + (bid >> 3);
    int by = (int)((129.0f - sqrtf(16641.0f - 8.0f * (float)swz)) * 0.5f);
    by = by < 0 ? 0 : (by > 63 ? 63 : by);
    while (by < 63 && (by + 1) * (129 - (by + 1)) / 2 <= swz) ++by;
    while (by > 0 && by * (129 - by) / 2 > swz) --by;
    const int bx = by + (swz - by * (129 - by) / 2);
    const bool diag = (bx == by);
    const int rowBase = by * PAN, colBase = bx * PAN;

    const int tid = threadIdx.x, lane = tid & 63, wid = tid >> 6;
    const int wm = wid >> 1, wn = wid & 1;
    const int rr = lane & 15, kh = lane >> 4;

    const int laneB = lane * 16;
    int voA[4], voB[4];
    #pragma unroll
    for (int i = 0; i < 4; ++i) {
        voA[i] = (wm * 4 + i) * 4096 + laneB;
        voB[i] = (wn * 4 + i) * 4096 + laneB;
    }
    const char* sbA = e8 + (size_t)rowBase * 256;
    const char* sbB = e8 + (size_t)colBase * 256;

    l2 pA[4], pB[4], qA[4], qB[4];
    ISSUE(pA, pB, "0");                                   // u=0 in flight
    ISSUE(qA, qB, "1024");                                // u=1 in flight

    if (tid < PAN) labR[tid] = labels[rowBase + tid];
    else           labC[tid - PAN] = labels[colBase + tid - PAN];

    f32x4 acc[4][4];
    #pragma unroll
    for (int i = 0; i < 4; ++i)
        #pragma unroll
        for (int j = 0; j < 4; ++j) acc[i][j] = (f32x4){0.f, 0.f, 0.f, 0.f};

    WAITV("8"); MFMA32(pA, pB);                           // u0
    ISSUE(pA, pB, "2048"); WAITV("8"); MFMA32(qA, qB);    // u=2 | u1
    ISSUE(qA, qB, "3072"); WAITV("8"); MFMA32(pA, pB);    // u=3 | u2
    WAITV("0"); MFMA32(qA, qB);                           //     | u3

    __syncthreads();   // labels visible

    int lc[4];
    #pragma unroll
    for (int ni = 0; ni < 4; ++ni) lc[ni] = labC[wn * 64 + ni * 16 + rr];
    float colA[4] = {0.f, 0.f, 0.f, 0.f}, colB[4] = {0.f, 0.f, 0.f, 0.f};

    #pragma unroll
    for (int mi = 0; mi < 4; ++mi) {
        #pragma unroll
        for (int r = 0; r < 4; ++r) {
            const int rowL = wm * 64 + mi * 16 + kh * 4 + r;
            const int lr = labR[rowL];
            float asum = 0.f, bsum = 0.f;
            #pragma unroll
            for (int ni = 0; ni < 4; ++ni) {
                const int colL = wn * 64 + ni * 16 + rr;
                const float val = acc[mi][ni][r];
                const bool pos = (lr == lc[ni]);
                float ex = exp2hw(pos ? -val : val);
                if (diag && rowL == colL) ex = 0.f;   // exclude self-pairs
                if (pos) { asum += ex; colA[ni] += ex; }
                else     { bsum += ex; colB[ni] += ex; }
            }
            asum = red16(asum);
            bsum = red16(bsum);
            if (rr == 0) { rowsc[wn][rowL][0] = asum; rowsc[wn][rowL][1] = bsum; }
        }
    }

    if (!diag) {
        #pragma unroll
        for (int ni = 0; ni < 4; ++ni) {
            float a = colA[ni], b = colB[ni];
            a += __shfl_xor(a, 16); a += __shfl_xor(a, 32);
            b += __shfl_xor(b, 16); b += __shfl_xor(b, 32);
            if (lane < 16) {
                colsc[wm][wn * 64 + ni * 16 + lane][0] = a;
                colsc[wm][wn * 64 + ni * 16 + lane][1] = b;
            }
        }
    }
    __syncthreads();

    if (tid < PAN) {
        const float ra = rowsc[0][tid][0] + rowsc[1][tid][0];
        const float rb = rowsc[0][tid][1] + rowsc[1][tid][1];
        wsAB[(size_t)bx * N_EMB + rowBase + tid] = packbf(ra, rb);
        if (!diag) {
            const float ca = colsc[0][tid][0] + colsc[1][tid][0];
            const float cb = colsc[0][tid][1] + colsc[1][tid][1];
            wsAB[(size_t)by * N_EMB + colBase + tid] = packbf(ca, cb);
        }
    }
}

// ----------------------------------------------- coalesced reduce + label bin
__global__ __launch_bounds__(256) void reduce_rows(const unsigned* __restrict__ wsAB,
                                                   const int* __restrict__ labels,
                                                   float* __restrict__ part) {
    __shared__ float sA[4][64], sB[4][64];
    __shared__ float binA[NUM_LABELS], binB[NUM_LABELS];
    __shared__ int binC[NUM_LABELS];
    const int tid = threadIdx.x, lane = tid & 63, wid = tid >> 6;
    if (tid < NUM_LABELS) { binA[tid] = 0.f; binB[tid] = 0.f; binC[tid] = 0; }
    const int rowBase = blockIdx.x * 64;
    float a = 0.f, b = 0.f;
    #pragma unroll
    for (int p = 0; p < 16; ++p) {
        const unsigned u = wsAB[(size_t)(wid * 16 + p) * N_EMB + rowBase + lane];
        a += __builtin_bit_cast(float, u << 16);
        b += __builtin_bit_cast(float, u & 0xFFFF0000u);
    }
    sA[wid][lane] = a; sB[wid][lane] = b;
    __syncthreads();
    if (tid < 64) {
        const float A = sA[0][tid] + sA[1][tid] + sA[2][tid] + sA[3][tid];
        const float B = sB[0][tid] + sB[1][tid] + sB[2][tid] + sB[3][tid];
        const int l = labels[rowBase + tid];
        atomicAdd(&binA[l], A);
        atomicAdd(&binB[l], B);
        atomicAdd(&binC[l], 1);
    }
    __syncthreads();
    if (tid < NUM_LABELS) {
        float* p = part + ((size_t)blockIdx.x * NUM_LABELS + tid) * 3;
        p[0] = binA[tid]; p[1] = binB[tid]; p[2] = (float)binC[tid];
    }
}

// ----------------------------------------------------------------- finalize
__global__ __launch_bounds__(128) void finalize_kernel(const float* __restrict__ part,
                                                       float* __restrict__ out) {
    const int g = threadIdx.x;
    float A = 0.f, B = 0.f, c = 0.f;
    #pragma unroll 8
    for (int b = 0; b < 128; ++b) {
        const float* p = part + ((size_t)b * NUM_LABELS + g) * 3;
        A += p[0]; B += p[1]; c += p[2];
    }
    float v = (c >= 2.f) ? A * B : 0.f;
    #pragma unroll
    for (int off = 32; off >= 1; off >>= 1) v += __shfl_xor(v, off);
    __shared__ float w2[2];
    if ((g & 63) == 0) w2[g >> 6] = v;
    __syncthreads();
    if (g == 0) out[0] = logf(1.0f + w2[0] + w2[1]);
}

// ------------------------------------------------------------------ launcher
extern "C" void kernel_launch(void* const* d_in, const int* in_sizes, int n_in,
                              void* d_out, int out_size, void* d_ws, size_t ws_size,
                              hipStream_t stream) {
    const float* emb    = (const float*)d_in[0];
    const int*   labels = (const int*)d_in[1];
    const float* scale  = (const float*)d_in[2];
    float* out = (float*)d_out;

    char* base = (char*)d_ws;
    char*     e8   = base;                                   // 2 MB
    unsigned* wsAB = (unsigned*)(base + (2u << 20));         // 2 MB
    float*    part = (float*)(base + (4u << 20));            // 192 KB

    normalize_kernel<<<N_EMB / 4, 256, 0, stream>>>(emb, scale, e8);
    // PROBE: launch main 3x (bit-identical output each time; deterministic).
    // main_us = (dur_r16 - dur_r15) / 2.
    cosent_main<<<NTRI, 256, 0, stream>>>(e8, labels, wsAB);
    cosent_main<<<NTRI, 256, 0, stream>>>(e8, labels, wsAB);
    cosent_main<<<NTRI, 256, 0, stream>>>(e8, labels, wsAB);
    reduce_rows<<<NUM_LABELS, 256, 0, stream>>>(wsAB, labels, part);
    finalize_kernel<<<1, 128, 0, stream>>>(part, out);
}

// Round 18
// 58.320 us; speedup vs baseline: 1.7665x; 1.7665x over previous
//
#include <hip/hip_runtime.h>
#include <hip/hip_bf16.h>
#include <math.h>

// CoSent clustering loss on MI355X — round 18.
// r15 (proven: main 27.6us, total 47.8us) + ONE change: finalize fused into
// reduce_rows via the CANONICAL threadfence-reduction pattern (r17's version
// raced: tid0 took the last-block ticket before its own block's part[] stores
// — __threadfence only orders the calling thread; need stores -> ALL-threads
// threadfence -> syncthreads -> tid0 atomic). Saves one launch + one gap.

typedef __attribute__((ext_vector_type(2))) long l2;     // two fp8 frags
typedef __attribute__((ext_vector_type(4))) float f32x4;

#define N_EMB 8192
#define D_EMB 256
#define NUM_LABELS 128
#define PAN 128
#define NPAN (N_EMB / PAN)           // 64
#define NTRI (NPAN * (NPAN + 1) / 2) // 2080 = 8 * 260

// ---- DPP 16-lane reduction helpers ----
template <int CTRL>
__device__ __forceinline__ float dpp_add(float x) {
    int y = __builtin_amdgcn_update_dpp(0, __builtin_bit_cast(int, x),
                                        CTRL, 0xF, 0xF, false);
    return x + __builtin_bit_cast(float, y);
}
__device__ __forceinline__ float red16(float x) {
    x = dpp_add<0xB1>(x);    // quad_perm xor1
    x = dpp_add<0x4E>(x);    // quad_perm xor2
    x = dpp_add<0x124>(x);   // row_ror:4
    x = dpp_add<0x128>(x);   // row_ror:8
    return x;
}

__device__ __forceinline__ float exp2hw(float x) {
    float r;
    asm("v_exp_f32 %0, %1" : "=v"(r) : "v"(x));
    return r;
}

__device__ __forceinline__ unsigned packbf(float a, float b) {
    unsigned ua = __builtin_bit_cast(unsigned, a);
    unsigned ub = __builtin_bit_cast(unsigned, b);
    ua += 0x7FFFu + ((ua >> 16) & 1u);   // RTNE to bf16
    ub += 0x7FFFu + ((ub >> 16) & 1u);
    return (ua >> 16) | (ub & 0xFFFF0000u);
}

// ---------------------------------------------------------------- normalize
// fp8 superfrag-major, PRESCALED by sqrt(s*log2e). Block 0 zeroes the
// last-block counter (int, deterministic).
__global__ __launch_bounds__(256) void normalize_kernel(const float* __restrict__ emb,
                                                        const float* __restrict__ scale,
                                                        char* __restrict__ e8,
                                                        int* __restrict__ counter) {
    const int wid = threadIdx.x >> 6, lane = threadIdx.x & 63;
    const int row = blockIdx.x * 4 + wid;
    const f32x4 x = *(const f32x4*)(emb + (size_t)row * D_EMB + lane * 4);
    float ss = x[0]*x[0] + x[1]*x[1] + x[2]*x[2] + x[3]*x[3];
    #pragma unroll
    for (int off = 32; off >= 1; off >>= 1) ss += __shfl_xor(ss, off);
    const float r = 1.0f / fmaxf(sqrtf(ss), 1e-12f);
    const float ps = sqrtf(scale[0] * 1.44269504088896f) * r;
    int v = __builtin_amdgcn_cvt_pk_fp8_f32(x[0] * ps, x[1] * ps, 0, false);
    v = __builtin_amdgcn_cvt_pk_fp8_f32(x[2] * ps, x[3] * ps, v, true);
    const int u    = lane >> 4;
    const int half = (lane >> 3) & 1;
    const int lp   = ((lane >> 1) & 3) * 16 + (row & 15);
    const int j0   = (lane & 1) * 4;
    char* dst = e8 + ((size_t)(row >> 4) * 4 + u) * 1024 + lp * 16 + half * 8 + j0;
    *(unsigned*)dst = (unsigned)v;
    if (blockIdx.x == 0 && threadIdx.x == 0) counter[0] = 0;
}

// ---- pinned coalesced superfrag load: SGPR base + VGPR offset + literal ----
#define LOADF(dst, voff, sb, OFFSTR) \
    asm volatile("global_load_dwordx4 %0, %1, %2 offset:" OFFSTR \
                 : "=v"(dst) : "v"(voff), "s"(sb))

#define ISSUE(PA_, PB_, OFFSTR) \
    LOADF(PA_[0], voA[0], sbA, OFFSTR); LOADF(PA_[1], voA[1], sbA, OFFSTR); \
    LOADF(PA_[2], voA[2], sbA, OFFSTR); LOADF(PA_[3], voA[3], sbA, OFFSTR); \
    LOADF(PB_[0], voB[0], sbB, OFFSTR); LOADF(PB_[1], voB[1], sbB, OFFSTR); \
    LOADF(PB_[2], voB[2], sbB, OFFSTR); LOADF(PB_[3], voB[3], sbB, OFFSTR)

#define WAITV(NSTR) \
    asm volatile("s_waitcnt vmcnt(" NSTR ")" ::: "memory"); \
    __builtin_amdgcn_sched_barrier(0)

#define MF8(a, b, c) __builtin_amdgcn_mfma_f32_16x16x32_fp8_fp8(a, b, c, 0, 0, 0)

#define MROW(PA_, PB_, mi, H) \
    acc[mi][0] = MF8(PA_[mi][H], PB_[0][H], acc[mi][0]); \
    acc[mi][1] = MF8(PA_[mi][H], PB_[1][H], acc[mi][1]); \
    acc[mi][2] = MF8(PA_[mi][H], PB_[2][H], acc[mi][2]); \
    acc[mi][3] = MF8(PA_[mi][H], PB_[3][H], acc[mi][3]);

#define MFMA32(PA_, PB_) \
    __builtin_amdgcn_s_setprio(1); \
    MROW(PA_, PB_, 0, 0) MROW(PA_, PB_, 1, 0) MROW(PA_, PB_, 2, 0) MROW(PA_, PB_, 3, 0) \
    MROW(PA_, PB_, 0, 1) MROW(PA_, PB_, 1, 1) MROW(PA_, PB_, 2, 1) MROW(PA_, PB_, 3, 1) \
    __builtin_amdgcn_s_setprio(0)

// ----------------------------------------------------------------- main GEMM
__global__ __launch_bounds__(256, 3) void cosent_main(const char* __restrict__ e8,
                                                      const int* __restrict__ labels,
                                                      unsigned* __restrict__ wsAB) {
    __shared__ float rowsc[2][PAN][2];
    __shared__ float colsc[2][PAN][2];
    __shared__ int labR[PAN], labC[PAN];

    // XCD-bijective swizzle (2080 = 8*260) + closed-form triangular decode.
    const int bid = blockIdx.x;
    const int swz = (bid & 7) * 260 + (bid >> 3);
    int by = (int)((129.0f - sqrtf(16641.0f - 8.0f * (float)swz)) * 0.5f);
    by = by < 0 ? 0 : (by > 63 ? 63 : by);
    while (by < 63 && (by + 1) * (129 - (by + 1)) / 2 <= swz) ++by;
    while (by > 0 && by * (129 - by) / 2 > swz) --by;
    const int bx = by + (swz - by * (129 - by) / 2);
    const bool diag = (bx == by);
    const int rowBase = by * PAN, colBase = bx * PAN;

    const int tid = threadIdx.x, lane = tid & 63, wid = tid >> 6;
    const int wm = wid >> 1, wn = wid & 1;
    const int rr = lane & 15, kh = lane >> 4;

    const int laneB = lane * 16;
    int voA[4], voB[4];
    #pragma unroll
    for (int i = 0; i < 4; ++i) {
        voA[i] = (wm * 4 + i) * 4096 + laneB;
        voB[i] = (wn * 4 + i) * 4096 + laneB;
    }
    const char* sbA = e8 + (size_t)rowBase * 256;
    const char* sbB = e8 + (size_t)colBase * 256;

    l2 pA[4], pB[4], qA[4], qB[4];
    ISSUE(pA, pB, "0");                                   // u=0 in flight
    ISSUE(qA, qB, "1024");                                // u=1 in flight

    // latency-fill work: label staging + acc init
    if (tid < PAN) labR[tid] = labels[rowBase + tid];
    else           labC[tid - PAN] = labels[colBase + tid - PAN];

    f32x4 acc[4][4];
    #pragma unroll
    for (int i = 0; i < 4; ++i)
        #pragma unroll
        for (int j = 0; j < 4; ++j) acc[i][j] = (f32x4){0.f, 0.f, 0.f, 0.f};

    WAITV("8"); MFMA32(pA, pB);                           // u0
    ISSUE(pA, pB, "2048"); WAITV("8"); MFMA32(qA, qB);    // u=2 | u1
    ISSUE(qA, qB, "3072"); WAITV("8"); MFMA32(pA, pB);    // u=3 | u2
    WAITV("0"); MFMA32(qA, qB);                           //     | u3

    __syncthreads();   // labels visible

    // ------------- fused epilogue: acc is already s*log2e*sim
    int lc[4];
    #pragma unroll
    for (int ni = 0; ni < 4; ++ni) lc[ni] = labC[wn * 64 + ni * 16 + rr];
    float colA[4] = {0.f, 0.f, 0.f, 0.f}, colB[4] = {0.f, 0.f, 0.f, 0.f};

    #pragma unroll
    for (int mi = 0; mi < 4; ++mi) {
        #pragma unroll
        for (int r = 0; r < 4; ++r) {
            const int rowL = wm * 64 + mi * 16 + kh * 4 + r;
            const int lr = labR[rowL];
            float asum = 0.f, bsum = 0.f;
            #pragma unroll
            for (int ni = 0; ni < 4; ++ni) {
                const int colL = wn * 64 + ni * 16 + rr;
                const float val = acc[mi][ni][r];
                const bool pos = (lr == lc[ni]);
                float ex = exp2hw(pos ? -val : val);
                if (diag && rowL == colL) ex = 0.f;   // exclude self-pairs
                if (pos) { asum += ex; colA[ni] += ex; }
                else     { bsum += ex; colB[ni] += ex; }
            }
            asum = red16(asum);
            bsum = red16(bsum);
            if (rr == 0) { rowsc[wn][rowL][0] = asum; rowsc[wn][rowL][1] = bsum; }
        }
    }

    if (!diag) {   // col-side (transposed contribution via symmetry)
        #pragma unroll
        for (int ni = 0; ni < 4; ++ni) {
            float a = colA[ni], b = colB[ni];
            a += __shfl_xor(a, 16); a += __shfl_xor(a, 32);
            b += __shfl_xor(b, 16); b += __shfl_xor(b, 32);
            if (lane < 16) {
                colsc[wm][wn * 64 + ni * 16 + lane][0] = a;
                colsc[wm][wn * 64 + ni * 16 + lane][1] = b;
            }
        }
    }
    __syncthreads();

    if (tid < PAN) {
        const float ra = rowsc[0][tid][0] + rowsc[1][tid][0];
        const float rb = rowsc[0][tid][1] + rowsc[1][tid][1];
        wsAB[(size_t)bx * N_EMB + rowBase + tid] = packbf(ra, rb);
        if (!diag) {
            const float ca = colsc[0][tid][0] + colsc[1][tid][0];
            const float cb = colsc[0][tid][1] + colsc[1][tid][1];
            wsAB[(size_t)by * N_EMB + colBase + tid] = packbf(ca, cb);
        }
    }
}

// -------------------- coalesced reduce + label bin + fused last-block finalize
// Canonical threadfence-reduction: part[] stores -> ALL-threads threadfence ->
// syncthreads -> tid0 atomic ticket -> last block (fixed-order sums) finalizes.
__global__ __launch_bounds__(256) void reduce_rows(const unsigned* __restrict__ wsAB,
                                                   const int* __restrict__ labels,
                                                   float* __restrict__ part,
                                                   int* __restrict__ counter,
                                                   float* __restrict__ out) {
    __shared__ float sA[4][64], sB[4][64];
    __shared__ float binA[NUM_LABELS], binB[NUM_LABELS];
    __shared__ int binC[NUM_LABELS];
    __shared__ int isLast;
    const int tid = threadIdx.x, lane = tid & 63, wid = tid >> 6;
    if (tid < NUM_LABELS) { binA[tid] = 0.f; binB[tid] = 0.f; binC[tid] = 0; }
    const int rowBase = blockIdx.x * 64;
    float a = 0.f, b = 0.f;
    #pragma unroll
    for (int p = 0; p < 16; ++p) {
        const unsigned u = wsAB[(size_t)(wid * 16 + p) * N_EMB + rowBase + lane];
        a += __builtin_bit_cast(float, u << 16);
        b += __builtin_bit_cast(float, u & 0xFFFF0000u);
    }
    sA[wid][lane] = a; sB[wid][lane] = b;
    __syncthreads();
    if (tid < 64) {
        const float A = sA[0][tid] + sA[1][tid] + sA[2][tid] + sA[3][tid];
        const float B = sB[0][tid] + sB[1][tid] + sB[2][tid] + sB[3][tid];
        const int l = labels[rowBase + tid];
        atomicAdd(&binA[l], A);
        atomicAdd(&binB[l], B);
        atomicAdd(&binC[l], 1);
    }
    __syncthreads();
    if (tid < NUM_LABELS) {
        float* p = part + ((size_t)blockIdx.x * NUM_LABELS + tid) * 3;
        p[0] = binA[tid]; p[1] = binB[tid]; p[2] = (float)binC[tid];
    }

    // ---- canonical last-block pattern ----
    __threadfence();                 // EVERY thread: flush its part[] stores
    __syncthreads();                 // all stores+fences in this block done
    if (tid == 0) isLast = (atomicAdd(counter, 1) == NUM_LABELS - 1);
    __syncthreads();
    if (!isLast) return;
    __threadfence();                 // acquire: other blocks' part[] visible

    float A = 0.f, B = 0.f, c = 0.f;
    if (tid < NUM_LABELS) {
        #pragma unroll 8
        for (int bk = 0; bk < NUM_LABELS; ++bk) {   // fixed order: deterministic
            const float* p = part + ((size_t)bk * NUM_LABELS + tid) * 3;
            A += p[0]; B += p[1]; c += p[2];
        }
    }
    float v = (tid < NUM_LABELS && c >= 2.f) ? A * B : 0.f;
    #pragma unroll
    for (int off = 32; off >= 1; off >>= 1) v += __shfl_xor(v, off);
    __shared__ float w2[4];
    if ((tid & 63) == 0) w2[tid >> 6] = v;
    __syncthreads();
    if (tid == 0) out[0] = logf(1.0f + w2[0] + w2[1] + w2[2] + w2[3]);
}

// ------------------------------------------------------------------ launcher
extern "C" void kernel_launch(void* const* d_in, const int* in_sizes, int n_in,
                              void* d_out, int out_size, void* d_ws, size_t ws_size,
                              hipStream_t stream) {
    const float* emb    = (const float*)d_in[0];
    const int*   labels = (const int*)d_in[1];
    const float* scale  = (const float*)d_in[2];
    float* out = (float*)d_out;

    char* base = (char*)d_ws;
    char*     e8      = base;                                // 2 MB
    unsigned* wsAB    = (unsigned*)(base + (2u << 20));      // 2 MB
    float*    part    = (float*)(base + (4u << 20));         // 192 KB
    int*      counter = (int*)(base + (4u << 20) + 256 * 1024);

    normalize_kernel<<<N_EMB / 4, 256, 0, stream>>>(emb, scale, e8, counter);
    cosent_main<<<NTRI, 256, 0, stream>>>(e8, labels, wsAB);
    reduce_rows<<<NUM_LABELS, 256, 0, stream>>>(wsAB, labels, part, counter, out);
}